// Round 9
// baseline (345.937 us; speedup 1.0000x reference)
//
#include <hip/hip_runtime.h>

// Problem constants (B=64, L=512, H=1024)
constexpr int BB = 64;
constexpr int LL = 512;
constexpr int HH = 1024;
constexpr int SPLITS = 16;            // split-K factor for all GEMMs
constexpr int NWORK_GEMM = 3 * 16 * SPLITS;   // 768 (r, n-tile, split) tiles
constexpr int CHUNKS = 1024;          // flash: 16 chunks/batch, 32 l-rows each

typedef float nt_float4 __attribute__((ext_vector_type(4)));

struct Args {
    const float* hs; const float* ho; const float* ha; const float* enc;
    const int* Fp;
    const float* W_as;  const float* W_so;  const float* W_oa;
    const float* Win_as; const float* Win_so; const float* Win_oa;
    const float* Wout_as; const float* Wout_so; const float* Wout_oa;
    float* partA; float* partC; float* partG;
    float* hx; float* wc; float* opm; float* ms;
    float* out;
};

// ---------------------------------------------------------------------------
// 64x64 (r, n-tile, split) GEMM tile, 512 threads (8 waves), 8 outputs/thread
// (2m x 4n). Small per-thread state (acc 8 + 2 prefetch float4) so
// __launch_bounds__(512,6) caps VGPR at 85 WITHOUT spilling -> 24 waves/CU.
// Accumulation order over kk identical to the proven 256-thr version ->
// bit-identical split-K partials.
// ---------------------------------------------------------------------------
template<int K0, int K1>
__device__ __forceinline__ void gemm_tile512(const float* __restrict__ a0,
                                             const float* __restrict__ a1,
                                             const float* __restrict__ w,
                                             float* __restrict__ part_r,
                                             int nt, int sp, int tid,
                                             float (*As)[64], float (*Ws)[64])
{
    constexpr int K = K0 + K1;
    constexpr int KRANGE = K / SPLITS;
    const int n0 = nt << 6;
    const int ks = sp * KRANGE;
    // staging indices
    const int ma  = tid >> 3;          // A row 0..63
    const int ka  = (tid & 7) << 2;    // A k-offset 0,4,..,28
    const int kw  = tid >> 4;          // W k row 0..31
    const int jw  = (tid & 15) << 2;   // W col offset
    // compute indices
    const int tn  = tid & 15;          // n quad
    const int m0  = (tid >> 4) << 1;   // m pair base 0..62

    float4 av, wv;
    {
        const int kg = ks + ka;
        const float* srcA = (K1 == 0 || kg < K0) ? (a0 + (size_t)ma * HH + kg)
                                                 : (a1 + (size_t)ma * HH + (kg - K0));
        av = *(const float4*)srcA;
        wv = *(const float4*)(w + (size_t)(ks + kw) * HH + n0 + jw);
    }

    float acc[2][4] = {};

    for (int kt = ks; kt < ks + KRANGE; kt += 32) {
        As[ka + 0][ma] = av.x; As[ka + 1][ma] = av.y;
        As[ka + 2][ma] = av.z; As[ka + 3][ma] = av.w;
        *(float4*)&Ws[kw][jw] = wv;
        __syncthreads();

        if (kt + 32 < ks + KRANGE) {
            const int kn = kt + 32;
            const int kg = kn + ka;
            const float* srcA = (K1 == 0 || kg < K0) ? (a0 + (size_t)ma * HH + kg)
                                                     : (a1 + (size_t)ma * HH + (kg - K0));
            av = *(const float4*)srcA;
            wv = *(const float4*)(w + (size_t)(kn + kw) * HH + n0 + jw);
        }

        #pragma unroll
        for (int kk = 0; kk < 32; kk++) {
            float2 a2 = *(const float2*)&As[kk][m0];
            float4 b4 = *(const float4*)&Ws[kk][tn << 2];
            acc[0][0] += a2.x * b4.x; acc[0][1] += a2.x * b4.y;
            acc[0][2] += a2.x * b4.z; acc[0][3] += a2.x * b4.w;
            acc[1][0] += a2.y * b4.x; acc[1][1] += a2.y * b4.y;
            acc[1][2] += a2.y * b4.z; acc[1][3] += a2.y * b4.w;
        }
        __syncthreads();
    }

    #pragma unroll
    for (int i = 0; i < 2; i++) {
        float* dst = part_r + (size_t)((sp << 6) + m0 + i) * HH + n0 + (tn << 2);
        *(float4*)dst = make_float4(acc[i][0], acc[i][1], acc[i][2], acc[i][3]);
    }
}

// ---------------------------------------------------------------------------
// Stage 1: partA = cat(.,.) @ W_x.  768 blocks x 512 thr.
// ---------------------------------------------------------------------------
__global__ __launch_bounds__(512, 6)
void k_gemmA(Args a)
{
    __shared__ __align__(16) float smem[4096];   // As[32][64] + Ws[32][64]
    const int wk = blockIdx.x, tid = threadIdx.x;
    const int r = wk >> 8, nt = wk & 15, sp = (wk >> 4) & 15;
    const float* a0 = (r == 0) ? a.ha : (r == 1) ? a.hs : a.ho;
    const float* a1 = (r == 0) ? a.hs : (r == 1) ? a.ho : a.ha;
    const float* w  = (r == 0) ? a.W_as : (r == 1) ? a.W_so : a.W_oa;
    gemm_tile512<1024, 1024>(a0, a1, w, a.partA + (size_t)r * SPLITS * 65536,
                             nt, sp, tid, (float(*)[64])smem, (float(*)[64])(smem + 2048));
}

// ---------------------------------------------------------------------------
// Stage 2 fused (proven round 8, re-threaded to 512): reduce+tanh own 64x64
// A-slice of partA into LDS, then GEMM with Win. nt==0 blocks write hx.
// LDS: As2[64][64] (16 KB) + Ws[32][64] (8 KB).
// ---------------------------------------------------------------------------
__global__ __launch_bounds__(512, 6)
void k_gemmC_fused(Args a)
{
    __shared__ __align__(16) float As2[64][64];
    __shared__ __align__(16) float Ws[32][64];
    const int wk = blockIdx.x, tid = threadIdx.x;
    const int r = wk >> 8, nt = wk & 15, sp = (wk >> 4) & 15;
    const int ks = sp << 6;                 // KRANGE = 64
    const int n0 = nt << 6;
    const float* pA = a.partA + (size_t)r * SPLITS * 65536;
    const float* w  = (r == 0) ? a.Win_as : (r == 1) ? a.Win_so : a.Win_oa;

    // Phase 1: reduce 16 splits + tanh -> As2[k][m] (and hx if nt==0).
    #pragma unroll
    for (int i = 0; i < 2; i++) {
        const int s  = i * 512 + tid;       // 1024 float4 slots
        const int m  = s >> 4;
        const int k4 = (s & 15) << 2;
        const float* p = pA + (size_t)m * HH + ks + k4;
        float4 v = *(const float4*)p;
        #pragma unroll 4
        for (int y = 1; y < SPLITS; y++) {
            float4 q = *(const float4*)(p + (size_t)y * 65536);
            v.x += q.x; v.y += q.y; v.z += q.z; v.w += q.w;
        }
        v.x = tanhf(v.x); v.y = tanhf(v.y); v.z = tanhf(v.z); v.w = tanhf(v.w);
        As2[k4 + 0][m] = v.x; As2[k4 + 1][m] = v.y;
        As2[k4 + 2][m] = v.z; As2[k4 + 3][m] = v.w;
        if (nt == 0)
            *(float4*)(a.hx + (size_t)r * 65536 + (size_t)m * HH + ks + k4) = v;
    }
    __syncthreads();

    // Phase 2: GEMM over the 64-wide k-window.
    const int kw = tid >> 4;
    const int jw = (tid & 15) << 2;
    const int tn = tid & 15;
    const int m0 = (tid >> 4) << 1;
    float acc[2][4] = {};
    float4 wv = *(const float4*)(w + (size_t)(ks + kw) * HH + n0 + jw);
    #pragma unroll
    for (int kt = 0; kt < 64; kt += 32) {
        *(float4*)&Ws[kw][jw] = wv;
        __syncthreads();
        if (kt + 32 < 64)
            wv = *(const float4*)(w + (size_t)(ks + kt + 32 + kw) * HH + n0 + jw);
        #pragma unroll
        for (int kk = 0; kk < 32; kk++) {
            float2 a2 = *(const float2*)&As2[kt + kk][m0];
            float4 b4 = *(const float4*)&Ws[kk][tn << 2];
            acc[0][0] += a2.x * b4.x; acc[0][1] += a2.x * b4.y;
            acc[0][2] += a2.x * b4.z; acc[0][3] += a2.x * b4.w;
            acc[1][0] += a2.y * b4.x; acc[1][1] += a2.y * b4.y;
            acc[1][2] += a2.y * b4.z; acc[1][3] += a2.y * b4.w;
        }
        __syncthreads();
    }

    #pragma unroll
    for (int i = 0; i < 2; i++) {
        float* dst = a.partC + (size_t)r * SPLITS * 65536
                   + (size_t)((sp << 6) + m0 + i) * HH + n0 + (tn << 2);
        *(float4*)dst = make_float4(acc[i][0], acc[i][1], acc[i][2], acc[i][3]);
    }
}

// ---------------------------------------------------------------------------
// Stage 3 fused flash: reduce tt rows from partC into LDS, then 32 l-rows
// of online-softmax attention (round-3-proven chunking: wave = 4 rows x 2 it).
// 1024 blocks x 256 thr -> hits the VGPR-limited 12 waves/CU cap.
// ---------------------------------------------------------------------------
__global__ __launch_bounds__(256)
void k_flash_fused(Args a)
{
    __shared__ __align__(16) float smem[3072 + 4096 + 32];
    float* tr_l = smem;                                   // [3][1024]
    float (*o_l)[HH]     = (float(*)[HH])(smem + 3072);   // [4][1024]
    float (*ms_sh)[3][2] = (float(*)[3][2])(smem + 3072 + 4096);
    const int chunk = blockIdx.x, tid = threadIdx.x;
    const int b    = chunk >> 4;
    const int lc   = chunk & 15;
    const int lane = tid & 63;
    const int wv   = tid >> 6;

    // Phase 0: tt[r][b][:] = sum over 16 splits of partC.
    #pragma unroll
    for (int i = 0; i < 3; i++) {
        const int s  = i * 256 + tid;        // 768 float4 slots
        const int rr = s >> 8;
        const int h4 = (s & 255) << 2;
        const float* p = a.partC + (size_t)rr * SPLITS * 65536 + (size_t)b * HH + h4;
        float4 v = *(const float4*)p;
        #pragma unroll 4
        for (int y = 1; y < SPLITS; y++) {
            float4 q = *(const float4*)(p + (size_t)y * 65536);
            v.x += q.x; v.y += q.y; v.z += q.z; v.w += q.w;
        }
        *(float4*)&tr_l[rr * 1024 + h4] = v;
    }
    __syncthreads();

    float4 tr[3][4];
    #pragma unroll
    for (int r = 0; r < 3; r++)
        #pragma unroll
        for (int v = 0; v < 4; v++)
            tr[r][v] = *(const float4*)&tr_l[r * 1024 + (lane << 2) + (v << 8)];

    float  m_run[3] = {-3.0e38f, -3.0e38f, -3.0e38f};
    float  S_run[3] = {0.f, 0.f, 0.f};
    float4 o_run[3][4];
    #pragma unroll
    for (int r = 0; r < 3; r++)
        #pragma unroll
        for (int v = 0; v < 4; v++)
            o_run[r][v] = make_float4(0.f, 0.f, 0.f, 0.f);

    const float* ebase = a.enc + ((size_t)b * LL + (lc << 5) + (wv << 2)) * HH + (lane << 2);

    for (int it = 0; it < 2; it++) {
        const float* e = ebase + (size_t)(it << 4) * HH;
        float4 ev[4][4];
        #pragma unroll
        for (int j = 0; j < 4; j++)
            #pragma unroll
            for (int v = 0; v < 4; v++)
                ev[j][v] = *(const float4*)(e + (size_t)j * HH + (v << 8));

        float s[3][4];
        #pragma unroll
        for (int j = 0; j < 4; j++) {
            float d0 = 0.f, d1 = 0.f, d2 = 0.f;
            #pragma unroll
            for (int v = 0; v < 4; v++) {
                const float4 x = ev[j][v];
                d0 += x.x * tr[0][v].x + x.y * tr[0][v].y + x.z * tr[0][v].z + x.w * tr[0][v].w;
                d1 += x.x * tr[1][v].x + x.y * tr[1][v].y + x.z * tr[1][v].z + x.w * tr[1][v].w;
                d2 += x.x * tr[2][v].x + x.y * tr[2][v].y + x.z * tr[2][v].z + x.w * tr[2][v].w;
            }
            #pragma unroll
            for (int off = 32; off > 0; off >>= 1) {
                d0 += __shfl_xor(d0, off);
                d1 += __shfl_xor(d1, off);
                d2 += __shfl_xor(d2, off);
            }
            s[0][j] = d0; s[1][j] = d1; s[2][j] = d2;
        }

        #pragma unroll
        for (int r = 0; r < 3; r++) {
            const float mb = fmaxf(fmaxf(s[r][0], s[r][1]), fmaxf(s[r][2], s[r][3]));
            const float mn_ = fmaxf(m_run[r], mb);
            const float alpha = __expf(m_run[r] - mn_);
            m_run[r] = mn_;
            float p[4];
            float psum = 0.f;
            #pragma unroll
            for (int j = 0; j < 4; j++) { p[j] = __expf(s[r][j] - mn_); psum += p[j]; }
            S_run[r] = S_run[r] * alpha + psum;
            #pragma unroll
            for (int v = 0; v < 4; v++) {
                float4 o = o_run[r][v];
                o.x *= alpha; o.y *= alpha; o.z *= alpha; o.w *= alpha;
                #pragma unroll
                for (int j = 0; j < 4; j++) {
                    const float4 x = ev[j][v];
                    o.x += p[j] * x.x; o.y += p[j] * x.y;
                    o.z += p[j] * x.z; o.w += p[j] * x.w;
                }
                o_run[r][v] = o;
            }
        }
    }

    __syncthreads();
    if (lane == 0) {
        #pragma unroll
        for (int r = 0; r < 3; r++) { ms_sh[wv][r][0] = m_run[r]; ms_sh[wv][r][1] = S_run[r]; }
    }

    #pragma unroll
    for (int r = 0; r < 3; r++) {
        __syncthreads();
        #pragma unroll
        for (int v = 0; v < 4; v++)
            *(float4*)&o_l[wv][(lane << 2) + (v << 8)] = o_run[r][v];
        __syncthreads();

        const float m0 = ms_sh[0][r][0], m1 = ms_sh[1][r][0];
        const float m2 = ms_sh[2][r][0], m3 = ms_sh[3][r][0];
        const float M = fmaxf(fmaxf(m0, m1), fmaxf(m2, m3));
        const float w0 = __expf(m0 - M), w1 = __expf(m1 - M);
        const float w2 = __expf(m2 - M), w3 = __expf(m3 - M);
        float4 q0 = *(const float4*)&o_l[0][tid << 2];
        float4 q1 = *(const float4*)&o_l[1][tid << 2];
        float4 q2 = *(const float4*)&o_l[2][tid << 2];
        float4 q3 = *(const float4*)&o_l[3][tid << 2];
        float4 acc;
        acc.x = w0 * q0.x + w1 * q1.x + w2 * q2.x + w3 * q3.x;
        acc.y = w0 * q0.y + w1 * q1.y + w2 * q2.y + w3 * q3.y;
        acc.z = w0 * q0.z + w1 * q1.z + w2 * q2.z + w3 * q3.z;
        acc.w = w0 * q0.w + w1 * q1.w + w2 * q2.w + w3 * q3.w;
        *(float4*)&a.opm[((size_t)chunk * 3 + r) * HH + (tid << 2)] = acc;
        if (tid == 0) {
            const float S = w0 * ms_sh[0][r][1] + w1 * ms_sh[1][r][1]
                          + w2 * ms_sh[2][r][1] + w3 * ms_sh[3][r][1];
            a.ms[((size_t)chunk * 3 + r) * 2 + 0] = M;
            a.ms[((size_t)chunk * 3 + r) * 2 + 1] = S;
        }
    }
}

// ---------------------------------------------------------------------------
// Stage 4: LSE-combine 16 chunks per (b, r) -> wc (round-3-proven).
// ---------------------------------------------------------------------------
__global__ __launch_bounds__(256)
void k_combine(Args a)
{
    const int b = blockIdx.x, r = blockIdx.y, tid = threadIdx.x;
    float mv[16], sv[16];
    float M = -3.0e38f;
    #pragma unroll
    for (int c = 0; c < 16; c++) {
        const int chunk = (b << 4) + c;
        mv[c] = a.ms[((size_t)chunk * 3 + r) * 2 + 0];
        sv[c] = a.ms[((size_t)chunk * 3 + r) * 2 + 1];
        M = fmaxf(M, mv[c]);
    }
    float S = 0.f;
    float4 acc = make_float4(0.f, 0.f, 0.f, 0.f);
    #pragma unroll
    for (int c = 0; c < 16; c++) {
        const float wgt = __expf(mv[c] - M);
        S += wgt * sv[c];
        const int chunk = (b << 4) + c;
        float4 q = *(const float4*)&a.opm[((size_t)chunk * 3 + r) * HH + (tid << 2)];
        acc.x += wgt * q.x; acc.y += wgt * q.y;
        acc.z += wgt * q.z; acc.w += wgt * q.w;
    }
    const float inv = 1.0f / S;
    acc.x *= inv; acc.y *= inv; acc.z *= inv; acc.w *= inv;
    *(float4*)&a.wc[(size_t)(r * BB + b) * HH + (tid << 2)] = acc;
}

// ---------------------------------------------------------------------------
// Stage 5: partG = cat(wc, hx) @ Wout_x.  768 blocks x 512 thr.
// ---------------------------------------------------------------------------
__global__ __launch_bounds__(512, 6)
void k_gemmG(Args a)
{
    __shared__ __align__(16) float smem[4096];
    const int wk = blockIdx.x, tid = threadIdx.x;
    const int r = wk >> 8, nt = wk & 15, sp = (wk >> 4) & 15;
    const float* a0 = a.wc + (size_t)r * 65536;
    const float* a1 = a.hx + (size_t)r * 65536;
    const float* w  = (r == 0) ? a.Wout_as : (r == 1) ? a.Wout_so : a.Wout_oa;
    gemm_tile512<1024, 1024>(a0, a1, w, a.partG + (size_t)r * SPLITS * 65536,
                             nt, sp, tid, (float(*)[64])smem, (float(*)[64])(smem + 2048));
}

// ---------------------------------------------------------------------------
// Stage 6: reduce partG + tanh + broadcast. 768 blocks: 4-way split over F
// per slot (redundant reduce is L2-cheap); was 192 blocks = 0.75/CU.
// ---------------------------------------------------------------------------
__global__ __launch_bounds__(256)
void k_bcast(Args a)
{
    const int bid  = blockIdx.x;
    const int i4   = (bid >> 2) * 256 + threadIdx.x;   // float4 slot 0..49151
    const int flat = i4 << 2;
    const int r    = flat >> 16;
    const int mn   = flat & 65535;
    const float* p = a.partG + (size_t)r * SPLITS * 65536 + mn;
    float4 s = *(const float4*)p;
    #pragma unroll
    for (int y = 1; y < SPLITS; y++) {
        float4 q = *(const float4*)(p + (size_t)y * 65536);
        s.x += q.x; s.y += q.y; s.z += q.z; s.w += q.w;
    }
    s.x = tanhf(s.x); s.y = tanhf(s.y); s.z = tanhf(s.z); s.w = tanhf(s.w);

    nt_float4 sv;
    sv.x = s.x; sv.y = s.y; sv.z = s.z; sv.w = s.w;

    const int F  = *a.Fp;
    const int fc = bid & 3;
    const int fchunk = (F + 3) >> 2;
    const int fb = fc * fchunk;
    const int fe = (fb + fchunk < F) ? fb + fchunk : F;
    const int bb = mn >> 10;
    const int hh = mn & 1023;
    float* o = a.out + ((size_t)(r * BB + bb) * F) * HH + hh;
    for (int f = fb; f < fe; f++)
        __builtin_nontemporal_store(sv, (nt_float4*)(o + (size_t)f * HH));
}

// ---------------------------------------------------------------------------
extern "C" void kernel_launch(void* const* d_in, const int* in_sizes, int n_in,
                              void* d_out, int out_size, void* d_ws, size_t ws_size,
                              hipStream_t stream)
{
    (void)in_sizes; (void)n_in; (void)out_size; (void)ws_size;
    float* ws = (float*)d_ws;

    Args a;
    a.hs  = (const float*)d_in[0];
    a.ho  = (const float*)d_in[1];
    a.ha  = (const float*)d_in[2];
    a.enc = (const float*)d_in[3];
    a.Fp  = (const int*)d_in[4];
    a.W_as    = (const float*)d_in[5];
    a.W_so    = (const float*)d_in[6];
    a.W_oa    = (const float*)d_in[7];
    a.Win_as  = (const float*)d_in[8];
    a.Win_so  = (const float*)d_in[9];
    a.Win_oa  = (const float*)d_in[10];
    a.Wout_as = (const float*)d_in[11];
    a.Wout_so = (const float*)d_in[12];
    a.Wout_oa = (const float*)d_in[13];

    a.partA = ws;                     // [3][16][64][1024] = 3,145,728 floats
    a.partC = ws + 3145728;           // [3][16][64][1024]
    a.partG = ws + 6291456;           // [3][16][64][1024]
    a.hx    = ws + 9437184;           // [3][64][1024]
    a.wc    = ws + 9633792;           // [3][64][1024]
    a.opm   = ws + 9830400;           // [1024][3][1024] = 3,145,728 floats
    a.ms    = ws + 12976128;          // [1024][3][2]
    a.out   = (float*)d_out;

    k_gemmA      <<<NWORK_GEMM, 512, 0, stream>>>(a);
    k_gemmC_fused<<<NWORK_GEMM, 512, 0, stream>>>(a);
    k_flash_fused<<<CHUNKS,     256, 0, stream>>>(a);
    k_combine    <<<dim3(64, 3), 256, 0, stream>>>(a);
    k_gemmG      <<<NWORK_GEMM, 512, 0, stream>>>(a);
    k_bcast      <<<768,        256, 0, stream>>>(a);
}